// Round 1
// baseline (565.122 us; speedup 1.0000x reference)
//
#include <hip/hip_runtime.h>

#define N_NODES   100000
#define N_EDGES   3200000
#define N_FEAT    128
#define HIDDEN    16
#define MLP_H     100
#define N_CLASSES 12
#define N_GRAPHS  512

// ---------------- degree count (in-degree via dst), self-loop added later ---
__global__ __launch_bounds__(256) void kDeg(const int* __restrict__ dst,
                                            int* __restrict__ deg) {
    int e = blockIdx.x * 256 + threadIdx.x;
    if (e < N_EDGES) atomicAdd(&deg[dst[e]], 1);
}

__global__ __launch_bounds__(256) void kDinv(const int* __restrict__ deg,
                                             float* __restrict__ dinv) {
    int i = blockIdx.x * 256 + threadIdx.x;
    if (i < N_NODES) dinv[i] = rsqrtf((float)deg[i] + 1.0f);  // +1 = self loop
}

// ---------------- h1 = x @ W1 ; agg1 = h1 * dinv^2 (self-loop seed) --------
__global__ __launch_bounds__(256) void kGemm1(const float* __restrict__ x,
                                              const float* __restrict__ W1,
                                              const float* __restrict__ dinv,
                                              float* __restrict__ h1,
                                              float* __restrict__ agg1) {
    __shared__ float Ws[N_FEAT * HIDDEN];  // 8 KB
    for (int t = threadIdx.x; t < N_FEAT * HIDDEN; t += 256) Ws[t] = W1[t];
    __syncthreads();
    int n = blockIdx.x * 256 + threadIdx.x;
    if (n >= N_NODES) return;

    float acc[HIDDEN];
#pragma unroll
    for (int j = 0; j < HIDDEN; ++j) acc[j] = 0.f;

    const float4* xr = (const float4*)(x + (size_t)n * N_FEAT);
#pragma unroll 4
    for (int k4 = 0; k4 < N_FEAT / 4; ++k4) {
        float4 v = xr[k4];
        float xk[4] = {v.x, v.y, v.z, v.w};
#pragma unroll
        for (int kk = 0; kk < 4; ++kk) {
            const float4* wrow = (const float4*)&Ws[(k4 * 4 + kk) * HIDDEN];
#pragma unroll
            for (int j4 = 0; j4 < 4; ++j4) {
                float4 wv = wrow[j4];
                acc[j4 * 4 + 0] += xk[kk] * wv.x;
                acc[j4 * 4 + 1] += xk[kk] * wv.y;
                acc[j4 * 4 + 2] += xk[kk] * wv.z;
                acc[j4 * 4 + 3] += xk[kk] * wv.w;
            }
        }
    }
    float dv = dinv[n];
    float dv2 = dv * dv;
    float4* h1r = (float4*)(h1 + (size_t)n * HIDDEN);
    float4* a1r = (float4*)(agg1 + (size_t)n * HIDDEN);
#pragma unroll
    for (int j4 = 0; j4 < 4; ++j4) {
        float4 hv = make_float4(acc[j4 * 4 + 0], acc[j4 * 4 + 1],
                                acc[j4 * 4 + 2], acc[j4 * 4 + 3]);
        h1r[j4] = hv;
        a1r[j4] = make_float4(hv.x * dv2, hv.y * dv2, hv.z * dv2, hv.w * dv2);
    }
}

// ---------------- scatter: agg[dst] += h[src] * dinv[src]*dinv[dst] --------
// 16 threads per edge: lane j handles feature j (contiguous 64B row access).
__global__ __launch_bounds__(256) void kScatter(const int* __restrict__ src,
                                                const int* __restrict__ dst,
                                                const float* __restrict__ dinv,
                                                const float* __restrict__ h,
                                                float* __restrict__ agg) {
    int gid = blockIdx.x * 256 + threadIdx.x;
    int e = gid >> 4;
    int j = gid & 15;
    if (e >= N_EDGES) return;
    int s = src[e];
    int d = dst[e];
    float w = dinv[s] * dinv[d];
    unsafeAtomicAdd(&agg[(size_t)d * HIDDEN + j],
                    h[(size_t)s * HIDDEN + j] * w);
}

// ------- t = relu(agg1+b1); h2 = t @ W2 ; agg2 = h2*dinv^2 -----------------
__global__ __launch_bounds__(256) void kLayer2(const float* __restrict__ agg1,
                                               const float* __restrict__ W2,
                                               const float* __restrict__ b1,
                                               const float* __restrict__ dinv,
                                               float* __restrict__ h2,
                                               float* __restrict__ agg2) {
    __shared__ float Ws[HIDDEN * HIDDEN];
    __shared__ float bs[HIDDEN];
    if (threadIdx.x < HIDDEN * HIDDEN) Ws[threadIdx.x] = W2[threadIdx.x];
    if (threadIdx.x < HIDDEN) bs[threadIdx.x] = b1[threadIdx.x];
    __syncthreads();
    int n = blockIdx.x * 256 + threadIdx.x;
    if (n >= N_NODES) return;

    float t[HIDDEN];
    const float4* a1r = (const float4*)(agg1 + (size_t)n * HIDDEN);
#pragma unroll
    for (int j4 = 0; j4 < 4; ++j4) {
        float4 av = a1r[j4];
        t[j4 * 4 + 0] = fmaxf(av.x + bs[j4 * 4 + 0], 0.f);
        t[j4 * 4 + 1] = fmaxf(av.y + bs[j4 * 4 + 1], 0.f);
        t[j4 * 4 + 2] = fmaxf(av.z + bs[j4 * 4 + 2], 0.f);
        t[j4 * 4 + 3] = fmaxf(av.w + bs[j4 * 4 + 3], 0.f);
    }
    float acc[HIDDEN];
#pragma unroll
    for (int j = 0; j < HIDDEN; ++j) acc[j] = 0.f;
#pragma unroll
    for (int k = 0; k < HIDDEN; ++k) {
        const float4* wrow = (const float4*)&Ws[k * HIDDEN];
#pragma unroll
        for (int j4 = 0; j4 < 4; ++j4) {
            float4 wv = wrow[j4];
            acc[j4 * 4 + 0] += t[k] * wv.x;
            acc[j4 * 4 + 1] += t[k] * wv.y;
            acc[j4 * 4 + 2] += t[k] * wv.z;
            acc[j4 * 4 + 3] += t[k] * wv.w;
        }
    }
    float dv = dinv[n];
    float dv2 = dv * dv;
    float4* h2r = (float4*)(h2 + (size_t)n * HIDDEN);
    float4* a2r = (float4*)(agg2 + (size_t)n * HIDDEN);
#pragma unroll
    for (int j4 = 0; j4 < 4; ++j4) {
        float4 hv = make_float4(acc[j4 * 4 + 0], acc[j4 * 4 + 1],
                                acc[j4 * 4 + 2], acc[j4 * 4 + 3]);
        h2r[j4] = hv;
        a2r[j4] = make_float4(hv.x * dv2, hv.y * dv2, hv.z * dv2, hv.w * dv2);
    }
}

// ------- v = relu(agg2+b2); pooled[batch[n]] += v --------------------------
__global__ __launch_bounds__(256) void kPool(const float* __restrict__ agg2,
                                             const float* __restrict__ b2,
                                             const int* __restrict__ batch,
                                             float* __restrict__ pooled) {
    int gid = blockIdx.x * 256 + threadIdx.x;
    int n = gid >> 4;
    int j = gid & 15;
    if (n >= N_NODES) return;
    float v = fmaxf(agg2[(size_t)n * HIDDEN + j] + b2[j], 0.f);
    unsafeAtomicAdd(&pooled[(size_t)batch[n] * HIDDEN + j], v);
}

// ------- g=relu(pooled); g1=relu(g@lw1+lb1); out=g1@lw2+lb2 ----------------
__global__ __launch_bounds__(64) void kMlp(const float* __restrict__ pooled,
                                           const float* __restrict__ lw1,
                                           const float* __restrict__ lb1,
                                           const float* __restrict__ lw2,
                                           const float* __restrict__ lb2,
                                           float* __restrict__ out) {
    int g = blockIdx.x * 64 + threadIdx.x;
    if (g >= N_GRAPHS) return;
    float gv[HIDDEN];
#pragma unroll
    for (int k = 0; k < HIDDEN; ++k)
        gv[k] = fmaxf(pooled[(size_t)g * HIDDEN + k], 0.f);
    float o[N_CLASSES];
#pragma unroll
    for (int c = 0; c < N_CLASSES; ++c) o[c] = lb2[c];
    for (int j = 0; j < MLP_H; ++j) {
        float s = lb1[j];
#pragma unroll
        for (int k = 0; k < HIDDEN; ++k) s += gv[k] * lw1[k * MLP_H + j];
        s = fmaxf(s, 0.f);
#pragma unroll
        for (int c = 0; c < N_CLASSES; ++c) o[c] += s * lw2[j * N_CLASSES + c];
    }
#pragma unroll
    for (int c = 0; c < N_CLASSES; ++c) out[(size_t)g * N_CLASSES + c] = o[c];
}

extern "C" void kernel_launch(void* const* d_in, const int* in_sizes, int n_in,
                              void* d_out, int out_size, void* d_ws,
                              size_t ws_size, hipStream_t stream) {
    const float* x     = (const float*)d_in[0];
    const int*   ei    = (const int*)d_in[1];
    const int*   batch = (const int*)d_in[2];
    const float* W1    = (const float*)d_in[3];
    const float* b1    = (const float*)d_in[4];
    const float* W2    = (const float*)d_in[5];
    const float* b2    = (const float*)d_in[6];
    const float* lw1   = (const float*)d_in[7];
    const float* lb1   = (const float*)d_in[8];
    const float* lw2   = (const float*)d_in[9];
    const float* lb2   = (const float*)d_in[10];
    float* out = (float*)d_out;

    const int* src = ei;
    const int* dst = ei + N_EDGES;

    // workspace layout (bytes, 16B aligned)
    char* ws = (char*)d_ws;
    int*   deg    = (int*)(ws + 0);           //   400000
    float* dinv   = (float*)(ws + 400000);    //   400000
    float* h1     = (float*)(ws + 800000);    //  6400000
    float* agg1   = (float*)(ws + 7200000);   //  6400000
    float* h2     = (float*)(ws + 13600000);  //  6400000
    float* agg2   = (float*)(ws + 20000000);  //  6400000
    float* pooled = (float*)(ws + 26400000);  //    32768

    hipMemsetAsync(deg, 0, 400000, stream);
    hipMemsetAsync(pooled, 0, 32768, stream);

    kDeg<<<(N_EDGES + 255) / 256, 256, 0, stream>>>(dst, deg);
    kDinv<<<(N_NODES + 255) / 256, 256, 0, stream>>>(deg, dinv);
    kGemm1<<<(N_NODES + 255) / 256, 256, 0, stream>>>(x, W1, dinv, h1, agg1);
    kScatter<<<(N_EDGES * 16) / 256, 256, 0, stream>>>(src, dst, dinv, h1, agg1);
    kLayer2<<<(N_NODES + 255) / 256, 256, 0, stream>>>(agg1, W2, b1, dinv, h2, agg2);
    kScatter<<<(N_EDGES * 16) / 256, 256, 0, stream>>>(src, dst, dinv, h2, agg2);
    kPool<<<(N_NODES * HIDDEN + 255) / 256, 256, 0, stream>>>(agg2, b2, batch, pooled);
    kMlp<<<(N_GRAPHS + 63) / 64, 64, 0, stream>>>(pooled, lw1, lb1, lw2, lb2, out);
}